// Round 6
// baseline (244.121 us; speedup 1.0000x reference)
//
#include <hip/hip_runtime.h>
#include <math.h>

// Problem constants (B, C, H, W) = (32, 10, 192, 320), fp32.
constexpr int B_ = 32, C_ = 10, H_ = 192, W_ = 320;
constexpr int HW_  = H_ * W_;        // 61440 floats per channel-image
constexpr int HW4_ = HW_ / 4;        // 15360 float4 per channel-image
constexpr int CHW_ = C_ * HW_;       // 614400
constexpr int T_   = 4;              // loop iterations per thread
constexpr int REG4 = 256 * T_;       // 1024 float4 per block-region
constexpr int RPI  = HW4_ / REG4;    // 15 block-regions per image
constexpr int NBLK = B_ * RPI;       // 480 blocks, exact cover

// Partial-sum slots, ws[slot * NBLK + blk], final weights folded in:
// 0: nv  1: num_pos
// 2: sum pos*(g0-r0)^2*log(safe+EPS)            (pos_term = -this)
// 3: sum neg*r0^2*log(1+EPS-safe)*(1-g0)^4      (neg_term = -this)
// 4: P  = 0.5*s_pos + 0.5*s_const + 0.1*s_h
// 5: V1 = 0.05*s_len1 + 0.5*s_trig1
// 6: V2 = 0.05*s_len2 + 0.5*s_trig2
// loss = focal + (P + min(V1,V2)) / nv
#define NACC 7

__device__ __forceinline__ float sl1f(float d) {
    float ad = fabsf(d);
    return ad < 1.0f ? 0.5f * d * d : ad - 0.5f;
}

// Round-6: loop-level software pipelining. Rounds 1-5 were one-shot waves
// (load-all, wait, compute, exit) and all plateaued at ~2.7 TB/s; the 6.3
// TB/s copy ubench is a multi-iteration loop where the compiler overlaps
// iter t+1 loads with iter t compute. Each thread: 4 iterations x float4,
// 20 paired loads per iteration consumed immediately (low live pressure).
__global__ __launch_bounds__(256, 4) void loss_main(
    const float* __restrict__ re, const float* __restrict__ gt,
    float* __restrict__ ws)
{
    const int img = blockIdx.x / RPI;           // image index
    const int reg = blockIdx.x - img * RPI;     // region within image
    // float4 index within image for iteration 0:
    const int s4_0 = reg * REG4 + threadIdx.x;
    const float* rbase = re + (size_t)img * CHW_;
    const float* gbase = gt + (size_t)img * CHW_;

    float acc[NACC];
#pragma unroll
    for (int i = 0; i < NACC; ++i) acc[i] = 0.0f;

#pragma unroll
    for (int t = 0; t < T_; ++t) {
        const int s = (s4_0 + t * 256) * 4;     // float offset in channel 0
        const float* rp = rbase + s;
        const float* gp = gbase + s;

        const float4 G0 = *(const float4*)(gp);
        const float4 R0 = *(const float4*)(rp);
        const float4 G1 = *(const float4*)(gp + 1 * HW_);
        const float4 R1 = *(const float4*)(rp + 1 * HW_);
        const float4 G2 = *(const float4*)(gp + 2 * HW_);
        const float4 R2 = *(const float4*)(rp + 2 * HW_);
        const float4 G3 = *(const float4*)(gp + 3 * HW_);
        const float4 R3 = *(const float4*)(rp + 3 * HW_);
        const float4 G4 = *(const float4*)(gp + 4 * HW_);
        const float4 R4 = *(const float4*)(rp + 4 * HW_);
        const float4 G5 = *(const float4*)(gp + 5 * HW_);
        const float4 R5 = *(const float4*)(rp + 5 * HW_);
        const float4 G6 = *(const float4*)(gp + 6 * HW_);
        const float4 R6 = *(const float4*)(rp + 6 * HW_);
        const float4 G7 = *(const float4*)(gp + 7 * HW_);
        const float4 R7 = *(const float4*)(rp + 7 * HW_);
        const float4 G8 = *(const float4*)(gp + 8 * HW_);
        const float4 R8 = *(const float4*)(rp + 8 * HW_);
        const float4 G9 = *(const float4*)(gp + 9 * HW_);
        const float4 R9 = *(const float4*)(rp + 9 * HW_);

#pragma unroll
        for (int j = 0; j < 4; ++j) {
            #define L(v) (((const float*)&v)[j])
            const float g = L(G0), r = L(R0);
            const float m = (g == 1.0f) ? 1.0f : 0.0f;
            acc[0] += m;
            const float pos = (g >= 0.1f) ? 1.0f : 0.0f;
            const float neg = ((g >= 0.0f) && (g < 0.1f)) ? 1.0f : 0.0f;
            acc[1] += pos;
            const float safe = fminf(fmaxf(r, 1e-6f), 1.0f - 1e-6f);
            const float d0 = g - r;
            acc[2] += pos * (d0 * d0) * logf(safe + 6e-8f);
            const float omg = 1.0f - g;
            const float omg2 = omg * omg;
            acc[3] += neg * (r * r) * logf(1.0f + 6e-8f - safe) * (omg2 * omg2);

            // P: 0.5*pos_ch + 0.5*const + 0.1*height
            const float sp = sl1f(L(R1) - L(G1)) + sl1f(L(R2) - L(G2));
            const float c1 = 1.0f - L(R5) * L(R5) - L(R4) * L(R4);
            const float c2 = 1.0f - L(R8) * L(R8) - L(R7) * L(R7);
            const float sc = c1 * c1 + c2 * c2;
            const float sh = sl1f(L(R9) - L(G9));
            acc[4] += m * (0.5f * sp + 0.5f * sc + 0.1f * sh);

            // V1: 0.05*len1 + 0.5*trig1
            const float d44 = L(R4) - L(G4), d77 = L(R7) - L(G7);
            const float d55 = L(R5) - L(G5), d88 = L(R8) - L(G8);
            const float t1 = d44 * d44 + d77 * d77 + d55 * d55 + d88 * d88;
            const float l1 = sl1f(L(R3) - L(G3)) + sl1f(L(R6) - L(G6));
            acc[5] += m * (0.05f * l1 + 0.5f * t1);

            // V2: 0.05*len2 + 0.5*trig2
            const float d47 = L(R4) - L(G7), d74 = L(R7) - L(G4);
            const float d58 = L(R5) - L(G8), d85 = L(R8) - L(G5);
            const float t2 = d47 * d47 + d74 * d74 + d58 * d58 + d85 * d85;
            const float l2 = sl1f(L(R3) - L(G6)) + sl1f(L(R6) - L(G3));
            acc[6] += m * (0.05f * l2 + 0.5f * t2);
            #undef L
        }
    }

    // block reduction: wave shuffle (64 lanes) -> LDS (4 waves) -> plain store
    __shared__ float smem[NACC][4];
    const int lane = threadIdx.x & 63;
    const int wid  = threadIdx.x >> 6;
#pragma unroll
    for (int i = 0; i < NACC; ++i) {
        float v = acc[i];
#pragma unroll
        for (int off = 32; off > 0; off >>= 1) v += __shfl_down(v, off, 64);
        if (lane == 0) smem[i][wid] = v;
    }
    __syncthreads();
    if (threadIdx.x < NACC) {
        const int i = threadIdx.x;
        ws[i * NBLK + blockIdx.x] =
            smem[i][0] + smem[i][1] + smem[i][2] + smem[i][3];
    }
}

// One block, 256 threads: reduce 480 partials per slot, apply loss formula.
__global__ __launch_bounds__(256) void loss_reduce(
    const float* __restrict__ ws, float* __restrict__ out)
{
    float acc[NACC];
#pragma unroll
    for (int i = 0; i < NACC; ++i) acc[i] = 0.0f;

#pragma unroll
    for (int k = 0; k < 2; ++k) {
        const int idx = threadIdx.x + k * 256;
        if (idx < NBLK) {
#pragma unroll
            for (int i = 0; i < NACC; ++i)
                acc[i] += ws[i * NBLK + idx];
        }
    }

    __shared__ float smem[NACC][4];
    const int lane = threadIdx.x & 63;
    const int wid  = threadIdx.x >> 6;
#pragma unroll
    for (int i = 0; i < NACC; ++i) {
        float v = acc[i];
#pragma unroll
        for (int off = 32; off > 0; off >>= 1) v += __shfl_down(v, off, 64);
        if (lane == 0) smem[i][wid] = v;
    }
    __syncthreads();

    if (threadIdx.x == 0) {
        float slot[NACC];
#pragma unroll
        for (int i = 0; i < NACC; ++i)
            slot[i] = smem[i][0] + smem[i][1] + smem[i][2] + smem[i][3];
        const float nv    = slot[0];
        const float npos  = slot[1];
        const float pterm = -slot[2];
        const float nterm = -slot[3];
        const float focal = (npos == 0.0f) ? nterm : (pterm + nterm) / npos;
        out[0] = focal + (slot[4] + fminf(slot[5], slot[6])) / nv;
    }
}

extern "C" void kernel_launch(void* const* d_in, const int* in_sizes, int n_in,
                              void* d_out, int out_size, void* d_ws, size_t ws_size,
                              hipStream_t stream)
{
    const float* re = (const float*)d_in[0];
    const float* gt = (const float*)d_in[1];
    float* ws  = (float*)d_ws;
    float* out = (float*)d_out;

    loss_main<<<NBLK, 256, 0, stream>>>(re, gt, ws);
    loss_reduce<<<1, 256, 0, stream>>>(ws, out);
}

// Round 7
// 178.843 us; speedup vs baseline: 1.3650x; 1.3650x over previous
//
#include <hip/hip_runtime.h>
#include <math.h>

// Problem constants (B, C, H, W) = (32, 10, 192, 320), fp32.
constexpr int B_ = 32, C_ = 10, H_ = 192, W_ = 320;
constexpr int HW_  = H_ * W_;        // 61440 floats per channel-image
constexpr int HW4_ = HW_ / 4;        // 15360 float4 per channel-image
constexpr int CHW_ = C_ * HW_;       // 614400
constexpr int SLICE4 = 512;          // float4 per stream per block
constexpr int T_  = SLICE4 / 256;    // 2 inner iterations
constexpr int SPI = HW4_ / SLICE4;   // 30 slices per channel-image
constexpr int BPG = B_ * SPI;        // 960 blocks per group
constexpr int NGRP = 5;
constexpr int NBLK = NGRP * BPG;     // 4800 blocks

// Partial-sum slots, ws[slot * NBLK + blk], final weights folded in:
// 0: nv  1: num_pos
// 2: sum pos*(g0-r0)^2*log(safe+EPS)            (pos_term = -this)
// 3: sum neg*r0^2*log(1+EPS-safe)*(1-g0)^4      (neg_term = -this)
// 4: P  = 0.5*s_pos + 0.5*s_const + 0.1*s_h
// 5: V1 = 0.05*s_len1 + 0.5*s_trig1
// 6: V2 = 0.05*s_len2 + 0.5*s_trig2
// loss = focal + (P + min(V1,V2)) / nv
#define NACC 7

__device__ __forceinline__ float sl1f(float d) {
    float ad = fabsf(d);
    return ad < 1.0f ? 0.5f * d * d : ad - 0.5f;
}

// Round-7: channel-group decomposition. Every previous round used a
// 20-interleaved-stream body, which the allocator always serializes or
// spills (round-6: 116 MB scratch WRITE). Here each block streams <=9
// contiguous channel-image slices (most groups 2-5), copy-loop style:
//   grp 0: re0,gt0            -> focal terms (slots 0-3)
//   grp 1: gt0, ch1,2 pairs   -> 0.5*s_pos            into slot 4
//   grp 2: gt0, ch3,6 pairs   -> 0.05*len1/len2       into slots 5,6
//   grp 3: gt0, ch4,5,7,8     -> 0.5*trig1/2 + const  into slots 4,5,6
//   grp 4: gt0, ch9 pair      -> 0.1*height           into slot 4
// Groups interleaved via blockIdx%5 for CU load balance; branch is
// block-uniform (no divergence). gt0 re-read by grps 1-4: +31 MB (+20%).
__global__ __launch_bounds__(256) void loss_main(
    const float* __restrict__ re, const float* __restrict__ gt,
    float* __restrict__ ws)
{
    const int grp = blockIdx.x % NGRP;
    const int wb  = blockIdx.x / NGRP;
    const int img = wb / SPI;
    const int sl  = wb - img * SPI;
    const float* rbase = re + (size_t)img * CHW_;
    const float* gbase = gt + (size_t)img * CHW_;
    const int f0 = sl * SLICE4 * 4;   // float offset of slice in channel-image

    float acc[NACC];
#pragma unroll
    for (int i = 0; i < NACC; ++i) acc[i] = 0.0f;

    if (grp == 0) {
        // focal: re0, gt0
        for (int t = 0; t < T_; ++t) {
            const int s = f0 + (t * 256 + threadIdx.x) * 4;
            const float4 G0 = *(const float4*)(gbase + s);
            const float4 R0 = *(const float4*)(rbase + s);
#pragma unroll
            for (int j = 0; j < 4; ++j) {
                const float g = ((const float*)&G0)[j];
                const float r = ((const float*)&R0)[j];
                acc[0] += (g == 1.0f) ? 1.0f : 0.0f;
                const float pos = (g >= 0.1f) ? 1.0f : 0.0f;
                const float neg = ((g >= 0.0f) && (g < 0.1f)) ? 1.0f : 0.0f;
                acc[1] += pos;
                const float safe = fminf(fmaxf(r, 1e-6f), 1.0f - 1e-6f);
                const float d0 = g - r;
                acc[2] += pos * (d0 * d0) * logf(safe + 6e-8f);
                const float omg = 1.0f - g;
                const float omg2 = omg * omg;
                acc[3] += neg * (r * r) * logf(1.0f + 6e-8f - safe) * (omg2 * omg2);
            }
        }
    } else if (grp == 1) {
        // pos channels 1,2
        for (int t = 0; t < T_; ++t) {
            const int s = f0 + (t * 256 + threadIdx.x) * 4;
            const float4 G0 = *(const float4*)(gbase + s);
            const float4 R1 = *(const float4*)(rbase + s + 1 * HW_);
            const float4 G1 = *(const float4*)(gbase + s + 1 * HW_);
            const float4 R2 = *(const float4*)(rbase + s + 2 * HW_);
            const float4 G2 = *(const float4*)(gbase + s + 2 * HW_);
#pragma unroll
            for (int j = 0; j < 4; ++j) {
                const float m = (((const float*)&G0)[j] == 1.0f) ? 1.0f : 0.0f;
                const float sp = sl1f(((const float*)&R1)[j] - ((const float*)&G1)[j])
                               + sl1f(((const float*)&R2)[j] - ((const float*)&G2)[j]);
                acc[4] += m * 0.5f * sp;
            }
        }
    } else if (grp == 2) {
        // length channels 3,6 (straight + swapped)
        for (int t = 0; t < T_; ++t) {
            const int s = f0 + (t * 256 + threadIdx.x) * 4;
            const float4 G0 = *(const float4*)(gbase + s);
            const float4 R3 = *(const float4*)(rbase + s + 3 * HW_);
            const float4 G3 = *(const float4*)(gbase + s + 3 * HW_);
            const float4 R6 = *(const float4*)(rbase + s + 6 * HW_);
            const float4 G6 = *(const float4*)(gbase + s + 6 * HW_);
#pragma unroll
            for (int j = 0; j < 4; ++j) {
                const float m = (((const float*)&G0)[j] == 1.0f) ? 1.0f : 0.0f;
                const float r3 = ((const float*)&R3)[j], g3 = ((const float*)&G3)[j];
                const float r6 = ((const float*)&R6)[j], g6 = ((const float*)&G6)[j];
                acc[5] += m * 0.05f * (sl1f(r3 - g3) + sl1f(r6 - g6));
                acc[6] += m * 0.05f * (sl1f(r3 - g6) + sl1f(r6 - g3));
            }
        }
    } else if (grp == 3) {
        // trig channels 4,5,7,8 (straight + swapped) + const
        for (int t = 0; t < T_; ++t) {
            const int s = f0 + (t * 256 + threadIdx.x) * 4;
            const float4 G0 = *(const float4*)(gbase + s);
            const float4 R4 = *(const float4*)(rbase + s + 4 * HW_);
            const float4 G4 = *(const float4*)(gbase + s + 4 * HW_);
            const float4 R5 = *(const float4*)(rbase + s + 5 * HW_);
            const float4 G5 = *(const float4*)(gbase + s + 5 * HW_);
            const float4 R7 = *(const float4*)(rbase + s + 7 * HW_);
            const float4 G7 = *(const float4*)(gbase + s + 7 * HW_);
            const float4 R8 = *(const float4*)(rbase + s + 8 * HW_);
            const float4 G8 = *(const float4*)(gbase + s + 8 * HW_);
#pragma unroll
            for (int j = 0; j < 4; ++j) {
                const float m = (((const float*)&G0)[j] == 1.0f) ? 1.0f : 0.0f;
                const float r4 = ((const float*)&R4)[j], g4 = ((const float*)&G4)[j];
                const float r5 = ((const float*)&R5)[j], g5 = ((const float*)&G5)[j];
                const float r7 = ((const float*)&R7)[j], g7 = ((const float*)&G7)[j];
                const float r8 = ((const float*)&R8)[j], g8 = ((const float*)&G8)[j];
                const float d44 = r4 - g4, d77 = r7 - g7;
                const float d55 = r5 - g5, d88 = r8 - g8;
                acc[5] += m * 0.5f * (d44 * d44 + d77 * d77 + d55 * d55 + d88 * d88);
                const float d47 = r4 - g7, d74 = r7 - g4;
                const float d58 = r5 - g8, d85 = r8 - g5;
                acc[6] += m * 0.5f * (d47 * d47 + d74 * d74 + d58 * d58 + d85 * d85);
                const float c1 = 1.0f - r5 * r5 - r4 * r4;
                const float c2 = 1.0f - r8 * r8 - r7 * r7;
                acc[4] += m * 0.5f * (c1 * c1 + c2 * c2);
            }
        }
    } else {
        // height channel 9
        for (int t = 0; t < T_; ++t) {
            const int s = f0 + (t * 256 + threadIdx.x) * 4;
            const float4 G0 = *(const float4*)(gbase + s);
            const float4 R9 = *(const float4*)(rbase + s + 9 * HW_);
            const float4 G9 = *(const float4*)(gbase + s + 9 * HW_);
#pragma unroll
            for (int j = 0; j < 4; ++j) {
                const float m = (((const float*)&G0)[j] == 1.0f) ? 1.0f : 0.0f;
                acc[4] += m * 0.1f * sl1f(((const float*)&R9)[j] - ((const float*)&G9)[j]);
            }
        }
    }

    // block reduction: wave shuffle (64 lanes) -> LDS (4 waves) -> plain store
    __shared__ float smem[NACC][4];
    const int lane = threadIdx.x & 63;
    const int wid  = threadIdx.x >> 6;
#pragma unroll
    for (int i = 0; i < NACC; ++i) {
        float v = acc[i];
#pragma unroll
        for (int off = 32; off > 0; off >>= 1) v += __shfl_down(v, off, 64);
        if (lane == 0) smem[i][wid] = v;
    }
    __syncthreads();
    if (threadIdx.x < NACC) {
        const int i = threadIdx.x;
        ws[i * NBLK + blockIdx.x] =
            smem[i][0] + smem[i][1] + smem[i][2] + smem[i][3];
    }
}

// One block, 1024 threads: reduce 4800 partials per slot, apply loss formula.
__global__ __launch_bounds__(1024) void loss_reduce(
    const float* __restrict__ ws, float* __restrict__ out)
{
    float acc[NACC];
#pragma unroll
    for (int i = 0; i < NACC; ++i) acc[i] = 0.0f;

#pragma unroll
    for (int k = 0; k < 5; ++k) {
        const int idx = threadIdx.x + k * 1024;
        if (idx < NBLK) {
#pragma unroll
            for (int i = 0; i < NACC; ++i)
                acc[i] += ws[i * NBLK + idx];
        }
    }

    __shared__ float smem[NACC][16];
    const int lane = threadIdx.x & 63;
    const int wid  = threadIdx.x >> 6;
#pragma unroll
    for (int i = 0; i < NACC; ++i) {
        float v = acc[i];
#pragma unroll
        for (int off = 32; off > 0; off >>= 1) v += __shfl_down(v, off, 64);
        if (lane == 0) smem[i][wid] = v;
    }
    __syncthreads();

    if (threadIdx.x == 0) {
        float slot[NACC];
#pragma unroll
        for (int i = 0; i < NACC; ++i) {
            float v = 0.0f;
#pragma unroll
            for (int w = 0; w < 16; ++w) v += smem[i][w];
            slot[i] = v;
        }
        const float nv    = slot[0];
        const float npos  = slot[1];
        const float pterm = -slot[2];
        const float nterm = -slot[3];
        const float focal = (npos == 0.0f) ? nterm : (pterm + nterm) / npos;
        out[0] = focal + (slot[4] + fminf(slot[5], slot[6])) / nv;
    }
}

extern "C" void kernel_launch(void* const* d_in, const int* in_sizes, int n_in,
                              void* d_out, int out_size, void* d_ws, size_t ws_size,
                              hipStream_t stream)
{
    const float* re = (const float*)d_in[0];
    const float* gt = (const float*)d_in[1];
    float* ws  = (float*)d_ws;
    float* out = (float*)d_out;

    loss_main<<<NBLK, 256, 0, stream>>>(re, gt, ws);
    loss_reduce<<<1, 1024, 0, stream>>>(ws, out);
}

// Round 8
// 178.398 us; speedup vs baseline: 1.3684x; 1.0025x over previous
//
#include <hip/hip_runtime.h>
#include <math.h>

// Problem constants (B, C, H, W) = (32, 10, 192, 320), fp32.
constexpr int B_    = 32, C_ = 10, H_ = 192, W_ = 320;
constexpr int HW_   = H_ * W_;        // 61440 floats per channel-image
constexpr int HW4_  = HW_ / 4;        // 15360 float4 per channel-image
constexpr int CHW_  = C_ * HW_;       // 614400 floats per image
constexpr int CHW4_ = CHW_ / 4;       // 153600 float4 per image
constexpr int N4_   = B_ * CHW4_;     // 4,915,200 float4 total per tensor
constexpr int T_    = 8;              // b-steps per thread
constexpr int NTHR  = N4_ / T_;       // 614,400 threads
constexpr int NBLK  = NTHR / 256;     // 2400 blocks
constexpr int BSTEP = NTHR / CHW4_;   // 4: b advances by 4 per iteration

// Partial-sum slots, ws[slot * NBLK + blk], final weights folded in:
// 0: nv  1: num_pos
// 2: sum pos*(g0-r0)^2*log(safe+EPS)            (pos_term = -this)
// 3: sum neg*r0^2*log(1+EPS-safe)*(1-g0)^4      (neg_term = -this)
// 4: P  = 0.5*s_pos + 0.5*s_const + 0.1*s_h
// 5: V1 = 0.05*s_len1 + 0.5*s_trig1
// 6: V2 = 0.05*s_len2 + 0.5*s_trig2
// loss = focal + (P + min(V1,V2)) / nv
#define NACC 7

__device__ __forceinline__ float sl1f(float d) {
    float ad = fabsf(d);
    return ad < 1.0f ? 0.5f * d * d : ad - 0.5f;
}

// Round-8: flat single-pass, copy-ubench-shaped. Each thread has a FIXED
// (channel, hw4) and walks the batch dimension (8 images, stride 4 images):
//   - channel is block-uniform (15360 float4/channel, 256-thread blocks
//     divide it exactly: 60 blocks/channel) -> zero divergence
//   - 2-5 unit-stride coalesced streams per thread (vs 9-20 in rounds 1-7)
//   - cross-channel partners (3<->6, 4<->7, 5<->8) via one extra stream;
//     gt0 mask stream is a 7.9 MB working set -> L2/L3 resident
__global__ __launch_bounds__(256) void loss_main(
    const float* __restrict__ re, const float* __restrict__ gt,
    float* __restrict__ ws)
{
    const int tid  = blockIdx.x * 256 + threadIdx.x;
    const int b0   = tid / CHW4_;          // 0..3, block-uniform
    const int slot = tid - b0 * CHW4_;     // (c, hw4)
    const int c    = slot / HW4_;          // block-uniform
    const int hw   = (slot - c * HW4_) * 4;

    const size_t base = (size_t)b0 * CHW_ + (size_t)c * HW_ + hw;
    const float* gch = gt + base;                          // gt[b, c, hw]
    const float* rch = re + base;                          // re[b, c, hw]
    const float* g0p = gt + (size_t)b0 * CHW_ + hw;        // gt[b, 0, hw]
    constexpr size_t STEP = (size_t)BSTEP * CHW_;          // 4 images

    float acc[NACC];
#pragma unroll
    for (int i = 0; i < NACC; ++i) acc[i] = 0.0f;

    #define ELEM(v) (((const float*)&v)[j])

    if (c == 0) {
        for (int k = 0; k < T_; ++k) {
            const float4 G = *(const float4*)(gch + k * STEP);
            const float4 R = *(const float4*)(rch + k * STEP);
#pragma unroll
            for (int j = 0; j < 4; ++j) {
                const float g = ELEM(G), r = ELEM(R);
                acc[0] += (g == 1.0f) ? 1.0f : 0.0f;
                const float pos = (g >= 0.1f) ? 1.0f : 0.0f;
                const float neg = ((g >= 0.0f) && (g < 0.1f)) ? 1.0f : 0.0f;
                acc[1] += pos;
                const float safe = fminf(fmaxf(r, 1e-6f), 1.0f - 1e-6f);
                const float d0 = g - r;
                acc[2] += pos * (d0 * d0) * logf(safe + 6e-8f);
                const float omg = 1.0f - g;
                const float omg2 = omg * omg;
                acc[3] += neg * (r * r) * logf(1.0f + 6e-8f - safe) * (omg2 * omg2);
            }
        }
    } else if (c == 1 || c == 2) {
        // 0.5 * sl1(r - g) -> P
        for (int k = 0; k < T_; ++k) {
            const float4 M = *(const float4*)(g0p + k * STEP);
            const float4 G = *(const float4*)(gch + k * STEP);
            const float4 R = *(const float4*)(rch + k * STEP);
#pragma unroll
            for (int j = 0; j < 4; ++j) {
                const float m = (ELEM(M) == 1.0f) ? 1.0f : 0.0f;
                acc[4] += m * 0.5f * sl1f(ELEM(R) - ELEM(G));
            }
        }
    } else if (c == 3 || c == 6) {
        // partner channel: 3<->6.  0.05*sl1(r-g) -> V1, 0.05*sl1(r-gx) -> V2
        const float* gxp = (c == 3) ? gch + 3 * HW_ : gch - 3 * HW_;
        for (int k = 0; k < T_; ++k) {
            const float4 M  = *(const float4*)(g0p + k * STEP);
            const float4 G  = *(const float4*)(gch + k * STEP);
            const float4 R  = *(const float4*)(rch + k * STEP);
            const float4 GX = *(const float4*)(gxp + k * STEP);
#pragma unroll
            for (int j = 0; j < 4; ++j) {
                const float m = (ELEM(M) == 1.0f) ? 1.0f : 0.0f;
                acc[5] += m * 0.05f * sl1f(ELEM(R) - ELEM(G));
                acc[6] += m * 0.05f * sl1f(ELEM(R) - ELEM(GX));
            }
        }
    } else if (c == 4 || c == 7) {
        // partner: 4<->7.  0.5*(r-g)^2 -> V1, 0.5*(r-gx)^2 -> V2
        const float* gxp = (c == 4) ? gch + 3 * HW_ : gch - 3 * HW_;
        for (int k = 0; k < T_; ++k) {
            const float4 M  = *(const float4*)(g0p + k * STEP);
            const float4 G  = *(const float4*)(gch + k * STEP);
            const float4 R  = *(const float4*)(rch + k * STEP);
            const float4 GX = *(const float4*)(gxp + k * STEP);
#pragma unroll
            for (int j = 0; j < 4; ++j) {
                const float m = (ELEM(M) == 1.0f) ? 1.0f : 0.0f;
                const float d1 = ELEM(R) - ELEM(G);
                const float d2 = ELEM(R) - ELEM(GX);
                acc[5] += m * 0.5f * d1 * d1;
                acc[6] += m * 0.5f * d2 * d2;
            }
        }
    } else if (c == 5 || c == 8) {
        // partner: 5<->8 (trig), plus const term needs r4 (resp r7) = rch-HW.
        const float* gxp = (c == 5) ? gch + 3 * HW_ : gch - 3 * HW_;
        const float* rxp = rch - HW_;
        for (int k = 0; k < T_; ++k) {
            const float4 M  = *(const float4*)(g0p + k * STEP);
            const float4 G  = *(const float4*)(gch + k * STEP);
            const float4 R  = *(const float4*)(rch + k * STEP);
            const float4 GX = *(const float4*)(gxp + k * STEP);
            const float4 RX = *(const float4*)(rxp + k * STEP);
#pragma unroll
            for (int j = 0; j < 4; ++j) {
                const float m = (ELEM(M) == 1.0f) ? 1.0f : 0.0f;
                const float r = ELEM(R), rx = ELEM(RX);
                const float d1 = r - ELEM(G);
                const float d2 = r - ELEM(GX);
                acc[5] += m * 0.5f * d1 * d1;
                acc[6] += m * 0.5f * d2 * d2;
                const float cc = 1.0f - r * r - rx * rx;
                acc[4] += m * 0.5f * cc * cc;
            }
        }
    } else {   // c == 9
        // 0.1 * sl1(r - g) -> P
        for (int k = 0; k < T_; ++k) {
            const float4 M = *(const float4*)(g0p + k * STEP);
            const float4 G = *(const float4*)(gch + k * STEP);
            const float4 R = *(const float4*)(rch + k * STEP);
#pragma unroll
            for (int j = 0; j < 4; ++j) {
                const float m = (ELEM(M) == 1.0f) ? 1.0f : 0.0f;
                acc[4] += m * 0.1f * sl1f(ELEM(R) - ELEM(G));
            }
        }
    }
    #undef ELEM

    // block reduction: wave shuffle (64 lanes) -> LDS (4 waves) -> plain store
    __shared__ float smem[NACC][4];
    const int lane = threadIdx.x & 63;
    const int wid  = threadIdx.x >> 6;
#pragma unroll
    for (int i = 0; i < NACC; ++i) {
        float v = acc[i];
#pragma unroll
        for (int off = 32; off > 0; off >>= 1) v += __shfl_down(v, off, 64);
        if (lane == 0) smem[i][wid] = v;
    }
    __syncthreads();
    if (threadIdx.x < NACC) {
        const int i = threadIdx.x;
        ws[i * NBLK + blockIdx.x] =
            smem[i][0] + smem[i][1] + smem[i][2] + smem[i][3];
    }
}

// One block, 1024 threads: reduce 2400 partials per slot, apply loss formula.
__global__ __launch_bounds__(1024) void loss_reduce(
    const float* __restrict__ ws, float* __restrict__ out)
{
    float acc[NACC];
#pragma unroll
    for (int i = 0; i < NACC; ++i) acc[i] = 0.0f;

#pragma unroll
    for (int k = 0; k < 3; ++k) {
        const int idx = threadIdx.x + k * 1024;
        if (idx < NBLK) {
#pragma unroll
            for (int i = 0; i < NACC; ++i)
                acc[i] += ws[i * NBLK + idx];
        }
    }

    __shared__ float smem[NACC][16];
    const int lane = threadIdx.x & 63;
    const int wid  = threadIdx.x >> 6;
#pragma unroll
    for (int i = 0; i < NACC; ++i) {
        float v = acc[i];
#pragma unroll
        for (int off = 32; off > 0; off >>= 1) v += __shfl_down(v, off, 64);
        if (lane == 0) smem[i][wid] = v;
    }
    __syncthreads();

    if (threadIdx.x == 0) {
        float slot[NACC];
#pragma unroll
        for (int i = 0; i < NACC; ++i) {
            float v = 0.0f;
#pragma unroll
            for (int w = 0; w < 16; ++w) v += smem[i][w];
            slot[i] = v;
        }
        const float nv    = slot[0];
        const float npos  = slot[1];
        const float pterm = -slot[2];
        const float nterm = -slot[3];
        const float focal = (npos == 0.0f) ? nterm : (pterm + nterm) / npos;
        out[0] = focal + (slot[4] + fminf(slot[5], slot[6])) / nv;
    }
}

extern "C" void kernel_launch(void* const* d_in, const int* in_sizes, int n_in,
                              void* d_out, int out_size, void* d_ws, size_t ws_size,
                              hipStream_t stream)
{
    const float* re = (const float*)d_in[0];
    const float* gt = (const float*)d_in[1];
    float* ws  = (float*)d_ws;
    float* out = (float*)d_out;

    loss_main<<<NBLK, 256, 0, stream>>>(re, gt, ws);
    loss_reduce<<<1, 1024, 0, stream>>>(ws, out);
}